// Round 1
// baseline (195.696 us; speedup 1.0000x reference)
//
#include <hip/hip_runtime.h>
#include <hip/hip_bf16.h>
#include <math.h>

// Problem constants (B,C,H,W) = (2,64,128,128), R=2 -> K=24 neighbors.
#define NNODES 16384            // H*W
#define GNODES 32768            // B*H*W
#define KE 24

// ---------------------------------------------------------------------------
// aux: zpos[k][h] = W1[h,128]*(dx/2) + W1[h,129]*(dy/2)
// ---------------------------------------------------------------------------
__global__ void aux_k(const float* __restrict__ W1, float* __restrict__ zpos)
{
    int t = threadIdx.x;
    for (int idx = t; idx < KE * 64; idx += 256) {
        int k = idx >> 6, h = idx & 63;
        int kk = k + (k >= 12 ? 1 : 0);       // skip center of 5x5
        int q5 = (kk * 52) >> 8;              // kk/5 for kk<25
        int dy = q5 - 2;
        int dx = kk - 5 * q5 - 2;
        zpos[idx] = W1[h * 130 + 128] * (dx * 0.5f)
                  + W1[h * 130 + 129] * (dy * 0.5f);
    }
}

// ---------------------------------------------------------------------------
// A: per-node precompute. zsrc' = nodes@W1a.T + b1 ; ztgt = nodes@W1b.T ;
//    msg = relu(nodes@Wm.T + bm).  64 nodes per block, 256 threads.
//    Weight reads are wave-uniform -> scalar loads.
// ---------------------------------------------------------------------------
__global__ __launch_bounds__(256) void precompute_k(
    const float* __restrict__ x, const float* __restrict__ W1,
    const float* __restrict__ b1, const float* __restrict__ Wm,
    const float* __restrict__ bm,
    float* __restrict__ zsrc, float* __restrict__ ztgt, float* __restrict__ msg)
{
    __shared__ float xt[64][65];   // xt[c][node]
    __shared__ float rt[64][65];   // rt[node][h]
    const int t = threadIdx.x;
    const int n0 = blockIdx.x * 64;
    const int b = n0 >> 14;
    const int nl0 = n0 & (NNODES - 1);
    const float* xb = x + (size_t)b * 64 * NNODES + nl0;

    #pragma unroll
    for (int rep = 0; rep < 16; ++rep) {
        int idx = rep * 256 + t;
        xt[idx >> 6][idx & 63] = xb[(size_t)(idx >> 6) * NNODES + (idx & 63)];
    }
    __syncthreads();

    const int lane = t & 63;   // node within tile
    const int wq = t >> 6;     // h-quarter (wave-uniform)

    #pragma unroll
    for (int mat = 0; mat < 3; ++mat) {
        float acc[16];
        #pragma unroll
        for (int m = 0; m < 16; ++m) acc[m] = 0.f;
        #pragma unroll 4
        for (int c = 0; c < 64; ++c) {
            float xv = xt[c][lane];
            #pragma unroll
            for (int m = 0; m < 16; ++m) {
                int h = wq * 16 + m;
                float wv = (mat == 0) ? W1[h * 130 + c]
                         : (mat == 1) ? W1[h * 130 + 64 + c]
                                      : Wm[h * 64 + c];
                acc[m] = fmaf(xv, wv, acc[m]);
            }
        }
        __syncthreads();   // prior rt consumers done
        #pragma unroll
        for (int m = 0; m < 16; ++m) {
            int h = wq * 16 + m;
            float v = acc[m];
            if (mat == 0) v += b1[h];
            if (mat == 2) v = fmaxf(v + bm[h], 0.f);
            rt[lane][h] = v;
        }
        __syncthreads();
        float* dst = (mat == 0) ? zsrc : (mat == 1) ? ztgt : msg;
        #pragma unroll
        for (int rep = 0; rep < 16; ++rep) {
            int idx = rep * 256 + t;
            dst[(size_t)(n0 + (idx >> 6)) * 64 + (idx & 63)] = rt[idx >> 6][idx & 63];
        }
    }
}

// ---------------------------------------------------------------------------
// B: thread-per-edge scorer. h1 in 64 VGPRs, W2 broadcast from LDS (float4),
//    fp32 throughout (top-k decisions are precision-sensitive).
// ---------------------------------------------------------------------------
__global__ __launch_bounds__(256) void score_k(
    const float* __restrict__ zsrc, const float* __restrict__ ztgt,
    const float* __restrict__ zpos, const float* __restrict__ W2,
    const float* __restrict__ b2, const float* __restrict__ W3,
    const float* __restrict__ b3, float* __restrict__ scores)
{
    __shared__ float4 w2s[512];   // W2[32][64] as float4
    const int t = threadIdx.x;
    for (int i = t; i < 512; i += 256) w2s[i] = ((const float4*)W2)[i];
    __syncthreads();

    const int eid = blockIdx.x * 256 + t;                       // exact grid
    const int n = (int)((((unsigned long long)(eid >> 3)) * 0xAAAAAAABull) >> 33); // eid/24
    const int k = eid - n * 24;
    const int b = n >> 14;
    const int nl = n & (NNODES - 1);
    const int yy = nl >> 7, xx = nl & 127;
    const int kk = k + (k >= 12 ? 1 : 0);
    const int q5 = (kk * 52) >> 8;
    const int dy = q5 - 2, dx = kk - 5 * q5 - 2;
    const int ny = min(max(yy + dy, 0), 127);
    const int nx = min(max(xx + dx, 0), 127);
    const int nb = (b << 14) + (ny << 7) + nx;

    const float4* za = (const float4*)(zsrc + (size_t)n * 64);
    const float4* zb = (const float4*)(ztgt + (size_t)nb * 64);
    const float4* zp = (const float4*)(zpos + k * 64);

    float h1[64];
    #pragma unroll
    for (int i4 = 0; i4 < 16; ++i4) {
        float4 a = za[i4], bt = zb[i4], p = zp[i4];
        h1[4 * i4 + 0] = fmaxf(a.x + bt.x + p.x, 0.f);
        h1[4 * i4 + 1] = fmaxf(a.y + bt.y + p.y, 0.f);
        h1[4 * i4 + 2] = fmaxf(a.z + bt.z + p.z, 0.f);
        h1[4 * i4 + 3] = fmaxf(a.w + bt.w + p.w, 0.f);
    }

    float spre = b3[0];
    #pragma unroll 4
    for (int j = 0; j < 32; ++j) {
        float a0 = 0.f, a1 = 0.f, a2 = 0.f, a3 = 0.f;
        #pragma unroll
        for (int i4 = 0; i4 < 16; ++i4) {
            float4 wv = w2s[j * 16 + i4];
            a0 = fmaf(h1[4 * i4 + 0], wv.x, a0);
            a1 = fmaf(h1[4 * i4 + 1], wv.y, a1);
            a2 = fmaf(h1[4 * i4 + 2], wv.z, a2);
            a3 = fmaf(h1[4 * i4 + 3], wv.w, a3);
        }
        float hj = fmaxf((a0 + a1) + (a2 + a3) + b2[j], 0.f);
        spre = fmaf(hj, W3[j], spre);
    }
    scores[eid] = 1.f / (1.f + expf(-spre));
}

// ---------------------------------------------------------------------------
// C: per-node rank/mask/weights + weighted msg aggregation + Wo + residual.
//    32 nodes per block. Stable rank matches lax.top_k tie semantics.
// ---------------------------------------------------------------------------
__global__ __launch_bounds__(256) void agg_k(
    const float* __restrict__ x, const float* __restrict__ scores,
    const float* __restrict__ msg, const float* __restrict__ Wo,
    const float* __restrict__ bo, const float* __restrict__ thrp,
    float* __restrict__ out)
{
    __shared__ float sc[768];
    __shared__ float wl[768];
    __shared__ float sumw[32];
    __shared__ float aggL[32][64];
    __shared__ float ot[64][33];
    __shared__ float4 WotL[1024];   // [c4][o] : Wo[o][4c4..4c4+3]

    const int t = threadIdx.x;
    const int n0 = blockIdx.x * 32;
    const int b = n0 >> 14;
    const int nl0 = n0 & (NNODES - 1);
    const float thr_v = 1.f / (1.f + expf(-thrp[0]));

    #pragma unroll
    for (int rep = 0; rep < 3; ++rep)
        sc[rep * 256 + t] = scores[(size_t)n0 * 24 + rep * 256 + t];
    for (int idx = t; idx < 1024; idx += 256) {
        int o = idx & 63, c4 = idx >> 6;
        WotL[c4 * 64 + o] = ((const float4*)Wo)[o * 16 + c4];
    }
    __syncthreads();

    // edge weights
    #pragma unroll
    for (int rep = 0; rep < 3; ++rep) {
        int e = rep * 256 + t;
        int nl = (int)(((unsigned)(e >> 3) * 171u) >> 9);   // e/24 for e<768
        int k = e - nl * 24;
        float s_e = sc[e];
        int rank = 0, cnt = 0;
        #pragma unroll
        for (int j = 0; j < 24; ++j) {
            float sj = sc[nl * 24 + j];
            rank += (sj > s_e || (sj == s_e && j < k)) ? 1 : 0;
            cnt  += (sj >= thr_v) ? 1 : 0;
        }
        bool mask = (cnt > 8) ? (rank < 8)
                  : ((cnt < 3) ? (rank < 3) : (s_e >= thr_v));
        float keep = 1.f / (1.f + expf(-(s_e - thr_v) * 10.f));
        wl[e] = mask ? s_e * keep : 0.f;
    }
    __syncthreads();

    if (t < 32) {
        float s = 0.f;
        #pragma unroll
        for (int k = 0; k < 24; ++k) s += wl[t * 24 + k];
        sumw[t] = s + 1e-6f;
    }
    __syncthreads();

    const int lane = t & 63;
    const int g4 = t >> 6;

    // weighted neighbor-message aggregation (msg rows coalesced 256B)
    #pragma unroll
    for (int it = 0; it < 8; ++it) {
        int nl = g4 + it * 4;
        int nn = nl0 + nl;
        int yy = nn >> 7, xx = nn & 127;
        float acc = 0.f;
        #pragma unroll
        for (int k = 0; k < 24; ++k) {
            int kk = k + (k >= 12 ? 1 : 0);
            int q5 = (kk * 52) >> 8;
            int dy = q5 - 2, dx = kk - 5 * q5 - 2;
            int ny = min(max(yy + dy, 0), 127);
            int nx = min(max(xx + dx, 0), 127);
            int nb = (b << 14) + (ny << 7) + nx;
            acc = fmaf(wl[nl * 24 + k], msg[(size_t)nb * 64 + lane], acc);
        }
        aggL[nl][lane] = acc / sumw[nl];
    }
    __syncthreads();

    // out = x + agg @ Wo.T + bo
    #pragma unroll
    for (int it = 0; it < 8; ++it) {
        int nl = g4 + it * 4;
        const float4* ar = (const float4*)aggL[nl];
        float a0 = 0.f, a1 = 0.f, a2 = 0.f, a3 = 0.f;
        #pragma unroll
        for (int c4 = 0; c4 < 16; ++c4) {
            float4 wv = WotL[c4 * 64 + lane];
            float4 av = ar[c4];
            a0 = fmaf(av.x, wv.x, a0);
            a1 = fmaf(av.y, wv.y, a1);
            a2 = fmaf(av.z, wv.z, a2);
            a3 = fmaf(av.w, wv.w, a3);
        }
        float v = (a0 + a1) + (a2 + a3) + bo[lane]
                + x[(size_t)b * 64 * NNODES + (size_t)lane * NNODES + nl0 + nl];
        ot[lane][nl] = v;
    }
    __syncthreads();

    // coalesced float4 stores (128B per o-row per block)
    #pragma unroll
    for (int rep = 0; rep < 2; ++rep) {
        int idx = rep * 256 + t;
        int o = idx >> 3, p = idx & 7;
        float4 v = make_float4(ot[o][4 * p + 0], ot[o][4 * p + 1],
                               ot[o][4 * p + 2], ot[o][4 * p + 3]);
        *(float4*)(out + (size_t)b * 64 * NNODES + (size_t)o * NNODES + nl0 + 4 * p) = v;
    }
}

// ---------------------------------------------------------------------------
extern "C" void kernel_launch(void* const* d_in, const int* in_sizes, int n_in,
                              void* d_out, int out_size, void* d_ws, size_t ws_size,
                              hipStream_t stream)
{
    const float* x   = (const float*)d_in[0];
    const float* W1  = (const float*)d_in[1];
    const float* b1  = (const float*)d_in[2];
    const float* W2  = (const float*)d_in[3];
    const float* b2  = (const float*)d_in[4];
    const float* W3  = (const float*)d_in[5];
    const float* b3  = (const float*)d_in[6];
    const float* thr = (const float*)d_in[7];
    const float* Wm  = (const float*)d_in[8];
    const float* bm  = (const float*)d_in[9];
    const float* Wo  = (const float*)d_in[10];
    const float* bo  = (const float*)d_in[11];
    float* out = (float*)d_out;
    float* ws  = (float*)d_ws;

    // ws layout (floats): zsrc[2M] ztgt[2M] msg[2M] scores[768K] zpos[1536]
    float* zsrc   = ws;
    float* ztgt   = ws + 2097152;
    float* msg    = ws + 4194304;
    float* scores = ws + 6291456;
    float* zpos   = ws + 7077888;

    hipLaunchKernelGGL(aux_k, dim3(1), dim3(256), 0, stream, W1, zpos);
    hipLaunchKernelGGL(precompute_k, dim3(512), dim3(256), 0, stream,
                       x, W1, b1, Wm, bm, zsrc, ztgt, msg);
    hipLaunchKernelGGL(score_k, dim3(3072), dim3(256), 0, stream,
                       zsrc, ztgt, zpos, W2, b2, W3, b3, scores);
    hipLaunchKernelGGL(agg_k, dim3(1024), dim3(256), 0, stream,
                       x, scores, msg, Wo, bo, thr, out);
}

// Round 2
// 146.596 us; speedup vs baseline: 1.3349x; 1.3349x over previous
//
#include <hip/hip_runtime.h>
#include <hip/hip_bf16.h>
#include <math.h>

// Problem constants (B,C,H,W) = (2,64,128,128), R=2 -> K=24 neighbors.
#define NNODES 16384            // H*W
#define GNODES 32768            // B*H*W
#define KE 24

// ---------------------------------------------------------------------------
// aux: zpos[k][h] table + W2T (transposed W2: [64][32]) for scalar-load access
// ---------------------------------------------------------------------------
__global__ void aux_k(const float* __restrict__ W1, const float* __restrict__ W2,
                      float* __restrict__ zpos, float* __restrict__ w2t)
{
    int t = threadIdx.x;
    for (int idx = t; idx < KE * 64; idx += 256) {
        int k = idx >> 6, h = idx & 63;
        int kk = k + (k >= 12 ? 1 : 0);       // skip center of 5x5
        int q5 = (kk * 52) >> 8;              // kk/5 for kk<25
        int dy = q5 - 2;
        int dx = kk - 5 * q5 - 2;
        zpos[idx] = W1[h * 130 + 128] * (dx * 0.5f)
                  + W1[h * 130 + 129] * (dy * 0.5f);
    }
    for (int idx = t; idx < 64 * 32; idx += 256) {
        int i = idx >> 5, j = idx & 31;       // w2t[i][j] = W2[j][i]
        w2t[idx] = W2[j * 64 + i];
    }
}

// ---------------------------------------------------------------------------
// A: per-node precompute. zsrc' = nodes@W1a.T + b1 ; ztgt = nodes@W1b.T ;
//    msg = relu(nodes@Wm.T + bm).  64 nodes per block, 256 threads.
//    Weight reads are wave-uniform -> scalar loads.
// ---------------------------------------------------------------------------
__global__ __launch_bounds__(256) void precompute_k(
    const float* __restrict__ x, const float* __restrict__ W1,
    const float* __restrict__ b1, const float* __restrict__ Wm,
    const float* __restrict__ bm,
    float* __restrict__ zsrc, float* __restrict__ ztgt, float* __restrict__ msg)
{
    __shared__ float xt[64][65];   // xt[c][node]
    __shared__ float rt[64][65];   // rt[node][h]
    const int t = threadIdx.x;
    const int n0 = blockIdx.x * 64;
    const int b = n0 >> 14;
    const int nl0 = n0 & (NNODES - 1);
    const float* xb = x + (size_t)b * 64 * NNODES + nl0;

    #pragma unroll
    for (int rep = 0; rep < 16; ++rep) {
        int idx = rep * 256 + t;
        xt[idx >> 6][idx & 63] = xb[(size_t)(idx >> 6) * NNODES + (idx & 63)];
    }
    __syncthreads();

    const int lane = t & 63;   // node within tile
    const int wq = t >> 6;     // h-quarter (wave-uniform)

    #pragma unroll
    for (int mat = 0; mat < 3; ++mat) {
        float acc[16];
        #pragma unroll
        for (int m = 0; m < 16; ++m) acc[m] = 0.f;
        #pragma unroll 4
        for (int c = 0; c < 64; ++c) {
            float xv = xt[c][lane];
            #pragma unroll
            for (int m = 0; m < 16; ++m) {
                int h = wq * 16 + m;
                float wv = (mat == 0) ? W1[h * 130 + c]
                         : (mat == 1) ? W1[h * 130 + 64 + c]
                                      : Wm[h * 64 + c];
                acc[m] = fmaf(xv, wv, acc[m]);
            }
        }
        __syncthreads();   // prior rt consumers done
        #pragma unroll
        for (int m = 0; m < 16; ++m) {
            int h = wq * 16 + m;
            float v = acc[m];
            if (mat == 0) v += b1[h];
            if (mat == 2) v = fmaxf(v + bm[h], 0.f);
            rt[lane][h] = v;
        }
        __syncthreads();
        float* dst = (mat == 0) ? zsrc : (mat == 1) ? ztgt : msg;
        #pragma unroll
        for (int rep = 0; rep < 16; ++rep) {
            int idx = rep * 256 + t;
            dst[(size_t)(n0 + (idx >> 6)) * 64 + (idx & 63)] = rt[idx >> 6][idx & 63];
        }
    }
}

// ---------------------------------------------------------------------------
// B: thread-per-edge scorer, streaming form. 32 persistent accumulators;
//    za/zb/zp each loaded exactly once; W2T read via wave-uniform scalar
//    loads (s_load) -> zero LDS, VALU-bound.
// ---------------------------------------------------------------------------
__global__ __launch_bounds__(256) void score_k(
    const float* __restrict__ zsrc, const float* __restrict__ ztgt,
    const float* __restrict__ zpos, const float* __restrict__ w2t,
    const float* __restrict__ b2, const float* __restrict__ W3,
    const float* __restrict__ b3, float* __restrict__ scores)
{
    const int t = threadIdx.x;
    const int eid = blockIdx.x * 256 + t;                       // exact grid
    const int n = (int)((((unsigned long long)(eid >> 3)) * 0xAAAAAAABull) >> 33); // eid/24
    const int k = eid - n * 24;
    const int b = n >> 14;
    const int nl = n & (NNODES - 1);
    const int yy = nl >> 7, xx = nl & 127;
    const int kk = k + (k >= 12 ? 1 : 0);
    const int q5 = (kk * 52) >> 8;
    const int dy = q5 - 2, dx = kk - 5 * q5 - 2;
    const int ny = min(max(yy + dy, 0), 127);
    const int nx = min(max(xx + dx, 0), 127);
    const int nb = (b << 14) + (ny << 7) + nx;

    const float4* za = (const float4*)(zsrc + (size_t)n * 64);
    const float4* zb = (const float4*)(ztgt + (size_t)nb * 64);
    const float4* zp = (const float4*)(zpos + k * 64);

    float acc[32];
    #pragma unroll
    for (int j = 0; j < 32; ++j) acc[j] = 0.f;

    for (int i4 = 0; i4 < 16; ++i4) {
        float4 a = za[i4], bt = zb[i4], p = zp[i4];
        float h[4];
        h[0] = fmaxf(a.x + bt.x + p.x, 0.f);
        h[1] = fmaxf(a.y + bt.y + p.y, 0.f);
        h[2] = fmaxf(a.z + bt.z + p.z, 0.f);
        h[3] = fmaxf(a.w + bt.w + p.w, 0.f);
        #pragma unroll
        for (int c = 0; c < 4; ++c) {
            const float* wrow = w2t + (i4 * 4 + c) * 32;   // uniform -> s_load
            #pragma unroll
            for (int j = 0; j < 32; ++j)
                acc[j] = fmaf(h[c], wrow[j], acc[j]);
        }
    }

    float spre = b3[0];
    #pragma unroll
    for (int j = 0; j < 32; ++j) {
        float hj = fmaxf(acc[j] + b2[j], 0.f);              // b2,W3 uniform -> s_load
        spre = fmaf(hj, W3[j], spre);
    }
    scores[eid] = 1.f / (1.f + expf(-spre));
}

// ---------------------------------------------------------------------------
// C: per-node rank/mask/weights + weighted msg aggregation + Wo + residual.
//    32 nodes per block. Stable rank matches lax.top_k tie semantics.
//    Wo row held in per-lane registers (no LDS broadcast matrix).
// ---------------------------------------------------------------------------
__global__ __launch_bounds__(256) void agg_k(
    const float* __restrict__ x, const float* __restrict__ scores,
    const float* __restrict__ msg, const float* __restrict__ Wo,
    const float* __restrict__ bo, const float* __restrict__ thrp,
    float* __restrict__ out)
{
    __shared__ float sc[768];
    __shared__ float wl[768];
    __shared__ float sumw[32];
    __shared__ float aggL[32][64];
    __shared__ float ot[64][33];

    const int t = threadIdx.x;
    const int n0 = blockIdx.x * 32;
    const int b = n0 >> 14;
    const int nl0 = n0 & (NNODES - 1);
    const float thr_v = 1.f / (1.f + expf(-thrp[0]));

    #pragma unroll
    for (int rep = 0; rep < 3; ++rep)
        sc[rep * 256 + t] = scores[(size_t)n0 * 24 + rep * 256 + t];
    __syncthreads();

    // edge weights
    #pragma unroll
    for (int rep = 0; rep < 3; ++rep) {
        int e = rep * 256 + t;
        int nl = (int)(((unsigned)(e >> 3) * 171u) >> 9);   // e/24 for e<768
        int k = e - nl * 24;
        float s_e = sc[e];
        int rank = 0, cnt = 0;
        #pragma unroll
        for (int j = 0; j < 24; ++j) {
            float sj = sc[nl * 24 + j];
            rank += (sj > s_e || (sj == s_e && j < k)) ? 1 : 0;
            cnt  += (sj >= thr_v) ? 1 : 0;
        }
        bool mask = (cnt > 8) ? (rank < 8)
                  : ((cnt < 3) ? (rank < 3) : (s_e >= thr_v));
        float keep = 1.f / (1.f + expf(-(s_e - thr_v) * 10.f));
        wl[e] = mask ? s_e * keep : 0.f;
    }
    __syncthreads();

    if (t < 32) {
        float s = 0.f;
        #pragma unroll
        for (int k = 0; k < 24; ++k) s += wl[t * 24 + k];
        sumw[t] = s + 1e-6f;
    }
    __syncthreads();

    const int lane = t & 63;
    const int g4 = t >> 6;

    // weighted neighbor-message aggregation (msg rows coalesced 256B)
    #pragma unroll
    for (int it = 0; it < 8; ++it) {
        int nl = g4 + it * 4;
        int nn = nl0 + nl;
        int yy = nn >> 7, xx = nn & 127;
        float acc = 0.f;
        #pragma unroll
        for (int k = 0; k < 24; ++k) {
            int kk = k + (k >= 12 ? 1 : 0);
            int q5 = (kk * 52) >> 8;
            int dy = q5 - 2, dx = kk - 5 * q5 - 2;
            int ny = min(max(yy + dy, 0), 127);
            int nx = min(max(xx + dx, 0), 127);
            int nb = (b << 14) + (ny << 7) + nx;
            acc = fmaf(wl[nl * 24 + k], msg[(size_t)nb * 64 + lane], acc);
        }
        aggL[nl][lane] = acc / sumw[nl];
    }

    // Wo row for this lane's output channel, kept in registers (L1-resident)
    float4 wo[16];
    #pragma unroll
    for (int c4 = 0; c4 < 16; ++c4) wo[c4] = ((const float4*)Wo)[lane * 16 + c4];
    __syncthreads();

    // out = x + agg @ Wo.T + bo
    #pragma unroll
    for (int it = 0; it < 8; ++it) {
        int nl = g4 + it * 4;
        const float4* ar = (const float4*)aggL[nl];
        float a0 = 0.f, a1 = 0.f, a2 = 0.f, a3 = 0.f;
        #pragma unroll
        for (int c4 = 0; c4 < 16; ++c4) {
            float4 wv = wo[c4];
            float4 av = ar[c4];
            a0 = fmaf(av.x, wv.x, a0);
            a1 = fmaf(av.y, wv.y, a1);
            a2 = fmaf(av.z, wv.z, a2);
            a3 = fmaf(av.w, wv.w, a3);
        }
        float v = (a0 + a1) + (a2 + a3) + bo[lane]
                + x[(size_t)b * 64 * NNODES + (size_t)lane * NNODES + nl0 + nl];
        ot[lane][nl] = v;
    }
    __syncthreads();

    // coalesced float4 stores (128B per o-row per block)
    #pragma unroll
    for (int rep = 0; rep < 2; ++rep) {
        int idx = rep * 256 + t;
        int o = idx >> 3, p = idx & 7;
        float4 v = make_float4(ot[o][4 * p + 0], ot[o][4 * p + 1],
                               ot[o][4 * p + 2], ot[o][4 * p + 3]);
        *(float4*)(out + (size_t)b * 64 * NNODES + (size_t)o * NNODES + nl0 + 4 * p) = v;
    }
}

// ---------------------------------------------------------------------------
extern "C" void kernel_launch(void* const* d_in, const int* in_sizes, int n_in,
                              void* d_out, int out_size, void* d_ws, size_t ws_size,
                              hipStream_t stream)
{
    const float* x   = (const float*)d_in[0];
    const float* W1  = (const float*)d_in[1];
    const float* b1  = (const float*)d_in[2];
    const float* W2  = (const float*)d_in[3];
    const float* b2  = (const float*)d_in[4];
    const float* W3  = (const float*)d_in[5];
    const float* b3  = (const float*)d_in[6];
    const float* thr = (const float*)d_in[7];
    const float* Wm  = (const float*)d_in[8];
    const float* bm  = (const float*)d_in[9];
    const float* Wo  = (const float*)d_in[10];
    const float* bo  = (const float*)d_in[11];
    float* out = (float*)d_out;
    float* ws  = (float*)d_ws;

    // ws layout (floats): zsrc[2M] ztgt[2M] msg[2M] scores[768K] zpos[1536] w2t[2048]
    float* zsrc   = ws;
    float* ztgt   = ws + 2097152;
    float* msg    = ws + 4194304;
    float* scores = ws + 6291456;
    float* zpos   = ws + 7077888;
    float* w2t    = ws + 7079424;

    hipLaunchKernelGGL(aux_k, dim3(1), dim3(256), 0, stream, W1, W2, zpos, w2t);
    hipLaunchKernelGGL(precompute_k, dim3(512), dim3(256), 0, stream,
                       x, W1, b1, Wm, bm, zsrc, ztgt, msg);
    hipLaunchKernelGGL(score_k, dim3(3072), dim3(256), 0, stream,
                       zsrc, ztgt, zpos, w2t, b2, W3, b3, scores);
    hipLaunchKernelGGL(agg_k, dim3(1024), dim3(256), 0, stream,
                       x, scores, msg, Wo, bo, thr, out);
}